// Round 7
// baseline (1411.148 us; speedup 1.0000x reference)
//
#include <hip/hip_runtime.h>
#include <cfloat>

// Problem dims (fixed): z_e [32,64,64,64] NCHW fp32, embedding [1024,64] fp32
// Flat rows n = b*4096 + h*64 + w  (N = 131072, D = 64, K = 1024)
// Out layout (concat, fp32): [0]=vq_loss, [1..8388608]=z_q NCHW,
//                            [8388609]=perplexity, [8388610..]=encodings [N,1024]
// ws layout: ws[0]=loss accum (float), ws[1..1024]=counts (int), ws[1025..2048]=e2 (float)

__global__ __launch_bounds__(256) void vq_prep(const float* __restrict__ emb,
                                               float* __restrict__ ws) {
  #pragma clang fp contract(off)
  int gid = blockIdx.x * 256 + threadIdx.x;   // 0..1023
  if (gid == 0) ws[0] = 0.0f;
  ((int*)ws)[1 + gid] = 0;
  // e2[k] = numpy-pairwise sum of squares over 64 elems
  const float* e = emb + (gid << 6);
  float r[8];
  #pragma unroll
  for (int j = 0; j < 8; ++j) r[j] = e[j] * e[j];
  #pragma unroll
  for (int i = 8; i < 64; i += 8) {
    #pragma unroll
    for (int j = 0; j < 8; ++j) { float s = e[i + j] * e[i + j]; r[j] = r[j] + s; }
  }
  ws[1025 + gid] = ((r[0] + r[1]) + (r[2] + r[3])) + ((r[4] + r[5]) + (r[6] + r[7]));
}

// R7: block = 8 waves = one 64-row group; wave w scans codes [128w,128w+128)
// via wave-private double-buffered LDS tiles (8 codes = 2KB), consumed as
// uniform-address ds_read_b128 broadcasts. lane = row; x[64] asm-pinned in
// VGPRs; per-lane argmin (bit-identical numerics). No barriers in the K-loop
// (DS in-order per wave). SGPR wall avoided (e never touches SGPRs); R5's
// VGPR explosion avoided (2 prefetch float4 regs, unroll-1 code loop).
__global__ __launch_bounds__(512, 4) void vq_main(const float* __restrict__ ze,
                                                  const float* __restrict__ emb,
                                                  float* __restrict__ ws,
                                                  float* __restrict__ out) {
  __shared__ float4 etile[8][2][128];  // [wave][buf][8 codes * 16 float4] = 32 KB
  __shared__ float  e2s[1024];         // 4 KB
  __shared__ float  sdist[8][64];      // 2 KB
  __shared__ int    sidx[8][64];       // 1 KB

  int tid  = threadIdx.x;
  int w    = __builtin_amdgcn_readfirstlane(tid >> 6);  // uniform wave id 0..7
  int lane = tid & 63;                 // row within group (= spatial w coord)
  int g    = blockIdx.x;               // row group 0..2047
  int b = g >> 6, h = g & 63;
  int n0 = g << 6;                     // first flat row of this group

  // ---- stage e2 into LDS (coalesced b32; avoids per-code s_load in the loop,
  //      which would share lgkmcnt with the ds stream and force drains) ----
  e2s[tid]       = ws[1025 + tid];
  e2s[512 + tid] = ws[1025 + 512 + tid];

  // ---- load x[64]: z_e[b, d, h, w], coalesced along w per d ----
  const float* xin = ze + (b << 18) + (h << 6) + lane;
  float x[64];
  #pragma unroll
  for (int d = 0; d < 64; ++d) x[d] = xin[d << 12];
  // Pin: asm-defined values can't be rematerialized -> x stays in 64 VGPRs.
  #pragma unroll
  for (int d = 0; d < 64; ++d) asm("" : "+v"(x[d]));

  // ---- x2: replicate numpy pairwise-sum order exactly ----
  float x2;
  {
    #pragma clang fp contract(off)
    float r[8];
    #pragma unroll
    for (int j = 0; j < 8; ++j) r[j] = x[j] * x[j];
    #pragma unroll
    for (int i = 8; i < 64; i += 8) {
      #pragma unroll
      for (int j = 0; j < 8; ++j) { float s = x[i + j] * x[i + j]; r[j] = r[j] + s; }
    }
    x2 = ((r[0] + r[1]) + (r[2] + r[3])) + ((r[4] + r[5]) + (r[6] + r[7]));
  }

  __syncthreads();   // e2s ready for all waves

  float* zq  = out + 1;
  float* enc = out + 8388610;

  int kw = w << 7;                     // wave's code base (uniform)
  const float4* E4 = (const float4*)emb;
  int f4base = kw << 4;                // kw*16 float4s

  // zero-stream: wave w zeroes a flat 32KB slice of the block's 256KB enc
  // region (contents are zeros -> flat coverage is fine). 64 float2/lane,
  // one 512B-contiguous wave-store per 2 codes. enc byte offs ≡8 mod 16 -> 8B ok.
  float2* encz = (float2*)enc + ((size_t)n0 << 9) + ((size_t)w << 12) + lane;
  const float2 z2 = make_float2(0.0f, 0.0f);

  // ---- prologue: stage tile 0 (8 codes = 2KB = 128 float4, 2 per lane) ----
  float4 p0 = E4[f4base + lane];
  float4 p1 = E4[f4base + 64 + lane];
  etile[w][0][lane]      = p0;
  etile[w][0][64 + lane] = p1;

  float best = FLT_MAX;
  int bidx = kw;
  int zi = 0;

  for (int t = 0; t < 16; ++t) {
    if (t < 15) {  // prefetch next tile into 2 regs (flies during compute)
      int fb = f4base + ((t + 1) << 7);
      p0 = E4[fb + lane];
      p1 = E4[fb + 64 + lane];
    }
    const float4* cur = &etile[w][t & 1][0];
    #pragma unroll 1   // cap ds_read hoisting: one code's 16 b128 in flight
    for (int c = 0; c < 8; ++c) {
      int k = kw + (t << 3) + c;
      const float4* ck = cur + (c << 4);  // uniform addr -> broadcast ds_read_b128
      float a0 = 0.0f, a1 = 0.0f, a2 = 0.0f, a3 = 0.0f;
      #pragma unroll
      for (int j = 0; j < 16; ++j) {
        float4 ev = ck[j];
        a0 = fmaf(x[(j << 2) + 0], ev.x, a0);
        a1 = fmaf(x[(j << 2) + 1], ev.y, a1);
        a2 = fmaf(x[(j << 2) + 2], ev.z, a2);
        a3 = fmaf(x[(j << 2) + 3], ev.w, a3);
      }
      float acc  = (a0 + a1) + (a2 + a3);
      float tt   = x2 + e2s[k];          // fl(x2 + e2) like numpy broadcast
      float dist = fmaf(-2.0f, acc, tt); // == fl(tt - fl(2*acc)); 2*acc exact
      if (dist < best) { best = dist; bidx = k; }  // strict < = first-index
      if (c & 1) { encz[(size_t)zi << 6] = z2; ++zi; }
    }
    if (t < 15) {  // write prefetched tile into the other buffer (DS in-order)
      float4* nb = &etile[w][(t + 1) & 1][0];
      nb[lane]      = p0;
      nb[64 + lane] = p1;
    }
  }

  // ---- cross-wave argmin combine (slices k-ordered by w; strict < keeps the
  //      lowest-w winner on ties = lowest k = numpy first-index argmin) ----
  sdist[w][lane] = best;
  sidx[w][lane]  = bidx;
  __syncthreads();   // also drains all zero-stream stores before 1.0 writes

  float gb = sdist[0][lane];
  int   gi = sidx[0][lane];
  #pragma unroll
  for (int j = 1; j < 8; ++j) {
    float dj = sdist[j][lane];
    int   ij = sidx[j][lane];
    if (dj < gb) { gb = dj; gi = ij; }
  }

  // ---- epilogue: wave 0 only; all x indices compile-time ----
  if (w == 0) {
    const float* esel = emb + (gi << 6);
    float* zqp = zq + (b << 18) + (h << 6) + lane;
    float lsum = 0.0f;
    #pragma unroll
    for (int d = 0; d < 64; ++d) {
      float v = esel[d];           // per-lane gather (256KB table, L2-resident)
      float df = v - x[d];
      lsum = fmaf(df, df, lsum);
      zqp[d << 12] = v;            // coalesced along w
    }
    #pragma unroll
    for (int off = 32; off > 0; off >>= 1) lsum += __shfl_down(lsum, off, 64);
    if (lane == 0) atomicAdd(ws, lsum);
    atomicAdd(&((int*)ws)[1 + gi], 1);
  }

  // one-hot 1.0: written by the slice-owning wave; the zero store to the same
  // address was drained at the barrier above.
  if ((gi >> 7) == w) {
    enc[((size_t)(n0 + lane) << 10) + gi] = 1.0f;
  }
}

__global__ __launch_bounds__(1024) void vq_fin(const float* __restrict__ ws,
                                               float* __restrict__ out) {
  __shared__ float sm[16];
  int t = threadIdx.x;  // 0..1023 = k
  const int* counts = (const int*)ws + 1;
  float c = (float)counts[t];
  float p = c * (1.0f / 131072.0f);
  float s = p * logf(p + 1e-10f);
  #pragma unroll
  for (int off = 32; off > 0; off >>= 1) s += __shfl_down(s, off, 64);
  if ((t & 63) == 0) sm[t >> 6] = s;
  __syncthreads();
  if (t == 0) {
    float v = 0.0f;
    #pragma unroll
    for (int i = 0; i < 16; ++i) v += sm[i];
    out[8388609] = expf(-v);               // perplexity
    float m = ws[0] / 8388608.0f;          // mean (z_q - z)^2
    out[0] = 0.25f * m + m;                // commitment + e2z
  }
}

extern "C" void kernel_launch(void* const* d_in, const int* in_sizes, int n_in,
                              void* d_out, int out_size, void* d_ws, size_t ws_size,
                              hipStream_t stream) {
  const float* ze  = (const float*)d_in[0];
  const float* emb = (const float*)d_in[1];
  float* out = (float*)d_out;
  float* ws  = (float*)d_ws;   // needs 2049 * 4B ≈ 8.2 KB
  vq_prep<<<4, 256, 0, stream>>>(emb, ws);
  vq_main<<<2048, 512, 0, stream>>>(ze, emb, ws, out);
  vq_fin<<<1, 1024, 0, stream>>>(ws, out);
}

// Round 8
// 664.931 us; speedup vs baseline: 2.1222x; 2.1222x over previous
//
#include <hip/hip_runtime.h>
#include <cfloat>
#include <stdint.h>

// Problem dims (fixed): z_e [32,64,64,64] NCHW fp32, embedding [1024,64] fp32
// Flat rows n = b*4096 + h*64 + w  (N = 131072, D = 64, K = 1024)
// Out layout (concat, fp32): [0]=vq_loss, [1..8388608]=z_q NCHW,
//                            [8388609]=perplexity, [8388610..]=encodings [N,1024]
// ws: [0]=loss accum, [1..1024]=counts (int), [1025..2048]=e2
//
// R8 architecture (the ≤64-VGPR law + scalar-path-BW wall force MFMA):
//  prep1: e2 exact pairwise + zero counts/loss
//  prep2: 3-way exact bf16 split of embedding -> MFMA B-fragment table,
//         stashed in the z_q region (overwritten later by pass 2)
//  k1:    per 64-row group: ip via 12x mfma_f32_16x16x32_bf16 per 16-code tile
//         (products hh,hm,mh,mm,hl,lh; ip err ~1e-9 ~ fp32 reorder noise),
//         dist = fmaf(-2, ip, x2+e2) == fl(t - fl(2ip)) bit-exact expression,
//         argmin via packed (distbits<<32)|code u64 min (first-index ties),
//         enc-zero stream fused; winners stashed in own enc slice head.
//  k2:    read winners -> z_q, enc 1.0s, loss partials, histogram
//  fin:   perplexity + vq_loss

typedef __attribute__((ext_vector_type(8))) short bf8v;
typedef __attribute__((ext_vector_type(4))) float f4v;

__device__ __forceinline__ unsigned short f2bf(float v) {  // RNE
  unsigned u = __float_as_uint(v);
  return (unsigned short)((u + 0x7FFFu + ((u >> 16) & 1u)) >> 16);
}
__device__ __forceinline__ float bf2f(unsigned short h) {
  return __uint_as_float(((unsigned)h) << 16);
}

__global__ __launch_bounds__(256) void vq_prep(const float* __restrict__ emb,
                                               float* __restrict__ ws) {
  #pragma clang fp contract(off)
  int gid = blockIdx.x * 256 + threadIdx.x;   // 0..1023
  if (gid == 0) ws[0] = 0.0f;
  ((int*)ws)[1 + gid] = 0;
  const float* e = emb + (gid << 6);
  float r[8];
  #pragma unroll
  for (int j = 0; j < 8; ++j) r[j] = e[j] * e[j];
  #pragma unroll
  for (int i = 8; i < 64; i += 8) {
    #pragma unroll
    for (int j = 0; j < 8; ++j) { float s = e[i + j] * e[i + j]; r[j] = r[j] + s; }
  }
  ws[1025 + gid] = ((r[0] + r[1]) + (r[2] + r[3])) + ((r[4] + r[5]) + (r[6] + r[7]));
}

// B-fragment table: entry e = ((nt*2+kk)*3+term)*64 + lane; 16B per entry.
// Lane ℓ of frag (nt,kk,term): codes c=16nt+(ℓ&15), k=32kk+8*(ℓ>>4)+j, j=0..7
// (mirrors the verified A layout A[m=lane&15][k=quad*8+j]; emb is row-major
// [code][d] = B^T, the m97 gemm_bt-validated pattern).
__global__ __launch_bounds__(256) void vq_prep_frags(const float* __restrict__ emb,
                                                     float* __restrict__ out) {
  int e = blockIdx.x * 256 + threadIdx.x;     // 0..24575
  int lane = e & 63, sub = e >> 6;
  int term = sub % 3, kk = (sub / 3) & 1, nt = sub / 6;
  int code = nt * 16 + (lane & 15);
  int d0 = kk * 32 + (lane >> 4) * 8;
  const float* src = emb + code * 64 + d0;
  unsigned short hs[8];
  #pragma unroll
  for (int j = 0; j < 8; ++j) {
    float v = src[j];
    unsigned short h = f2bf(v);  float r1 = v - bf2f(h);   // exact residual
    unsigned short m = f2bf(r1); float r2 = r1 - bf2f(m);  // exact residual
    unsigned short l = f2bf(r2);                           // exact (<=8 bits left)
    hs[j] = (term == 0) ? h : (term == 1) ? m : l;
  }
  uint4 p;
  p.x = (unsigned)hs[0] | ((unsigned)hs[1] << 16);
  p.y = (unsigned)hs[2] | ((unsigned)hs[3] << 16);
  p.z = (unsigned)hs[4] | ((unsigned)hs[5] << 16);
  p.w = (unsigned)hs[6] | ((unsigned)hs[7] << 16);
  ((uint4*)(out + 4))[e] = p;   // out+4 floats = +16B -> 16B aligned
}

__global__ __launch_bounds__(256, 4) void vq_main(const float* __restrict__ ze,
                                                  float* __restrict__ ws,
                                                  float* __restrict__ out) {
  __shared__ float xtile[64 * 68];                 // padded x tile (17.4 KB)
  __shared__ __align__(16) short bbuf[2 * 6 * 64 * 8];  // B-frag dbuf (12 KB)
  __shared__ float e2s[1024];
  __shared__ float x2s[64];
  __shared__ float sx[256];

  int t = threadIdx.x;
  int w = __builtin_amdgcn_readfirstlane(t >> 6);  // wave id = m-tile 0..3
  int lane = t & 63;
  int g = blockIdx.x;
  int b = g >> 6, h = g & 63;
  int n0 = g << 6;

  // ---- stage x tile (row = spatial w = lane) + e2 ----
  const float* zebase = ze + ((size_t)b << 18) + (h << 6);
  #pragma unroll
  for (int i = 0; i < 16; ++i) {
    int d = w * 16 + i;
    xtile[lane * 68 + d] = zebase[d * 4096 + lane];
  }
  e2s[t] = ws[1025 + t];         e2s[256 + t] = ws[1281 + t];
  e2s[512 + t] = ws[1537 + t];   e2s[768 + t] = ws[1793 + t];
  __syncthreads();

  // ---- x2: numpy pairwise order, exactly; thread (row=lane, a=w) does r[2a],r[2a+1]
  {
    #pragma clang fp contract(off)
    const float* xr = xtile + lane * 68;
    int j0 = 2 * w, j1 = 2 * w + 1;
    float v0 = xr[j0], v1 = xr[j1];
    float ra = v0 * v0, rb = v1 * v1;
    #pragma unroll
    for (int p = 1; p < 8; ++p) {
      float s0 = xr[8 * p + j0]; s0 = s0 * s0; ra = ra + s0;
      float s1 = xr[8 * p + j1]; s1 = s1 * s1; rb = rb + s1;
    }
    sx[lane * 4 + w] = ra + rb;
  }
  __syncthreads();
  if (t < 64) x2s[t] = (sx[t * 4] + sx[t * 4 + 1]) + (sx[t * 4 + 2] + sx[t * 4 + 3]);
  __syncthreads();

  // ---- A-frags (VGPR-resident, built once): rows w*16..w*16+15 ----
  int qd = lane >> 4, rr = lane & 15;
  const float* xr = xtile + (w * 16 + rr) * 68;
  bf8v Ah[2], Am[2], Al[2];
  #pragma unroll
  for (int kk = 0; kk < 2; ++kk) {
    #pragma unroll
    for (int j = 0; j < 8; ++j) {
      float v = xr[kk * 32 + qd * 8 + j];
      unsigned short hh = f2bf(v);  float r1 = v - bf2f(hh);
      unsigned short mm = f2bf(r1); float r2 = r1 - bf2f(mm);
      unsigned short ll = f2bf(r2);
      Ah[kk][j] = (short)hh; Am[kk][j] = (short)mm; Al[kk][j] = (short)ll;
    }
  }
  float x2v[4];
  #pragma unroll
  for (int r = 0; r < 4; ++r) x2v[r] = x2s[w * 16 + qd * 4 + r];

  const uint4* ft = (const uint4*)(out + 4);
  uint4* bput = (uint4*)bbuf;
  float* encbase = out + 8388610 + (size_t)n0 * 1024;
  const float2 z2 = make_float2(0.0f, 0.0f);

  // prologue: stage nt=0 frags (wave w stages f = w, w+4)
  for (int f = w; f < 6; f += 4) bput[f * 64 + lane] = ft[f * 64 + lane];
  __syncthreads();

  unsigned long long best[4] = {~0ULL, ~0ULL, ~0ULL, ~0ULL};

  #pragma unroll 1
  for (int nt = 0; nt < 64; ++nt) {
    int cur = nt & 1, nxt = cur ^ 1;
    uint4 pv0, pv1;
    if (nt < 63) {                       // issue next-tile loads early
      pv0 = ft[((nt + 1) * 6 + w) * 64 + lane];
      if (w < 2) pv1 = ft[((nt + 1) * 6 + w + 4) * 64 + lane];
    }
    float e2v = e2s[nt * 16 + (lane & 15)];
    f4v acc = {0.0f, 0.0f, 0.0f, 0.0f};
    const bf8v* bb = (const bf8v*)bbuf + cur * 6 * 64;
    #pragma unroll
    for (int kk = 0; kk < 2; ++kk) {
      bf8v Bh = bb[(kk * 3 + 0) * 64 + lane];
      bf8v Bm = bb[(kk * 3 + 1) * 64 + lane];
      bf8v Bl = bb[(kk * 3 + 2) * 64 + lane];
      acc = __builtin_amdgcn_mfma_f32_16x16x32_bf16(Ah[kk], Bh, acc, 0, 0, 0);
      acc = __builtin_amdgcn_mfma_f32_16x16x32_bf16(Ah[kk], Bm, acc, 0, 0, 0);
      acc = __builtin_amdgcn_mfma_f32_16x16x32_bf16(Am[kk], Bh, acc, 0, 0, 0);
      acc = __builtin_amdgcn_mfma_f32_16x16x32_bf16(Am[kk], Bm, acc, 0, 0, 0);
      acc = __builtin_amdgcn_mfma_f32_16x16x32_bf16(Ah[kk], Bl, acc, 0, 0, 0);
      acc = __builtin_amdgcn_mfma_f32_16x16x32_bf16(Al[kk], Bh, acc, 0, 0, 0);
    }
    unsigned code0 = (unsigned)(nt * 16 + (lane & 15));
    #pragma unroll
    for (int r = 0; r < 4; ++r) {
      float tt = x2v[r] + e2v;                 // fl(x2+e2) like numpy
      float dd = fmaf(-2.0f, acc[r], tt);      // == fl(t - fl(2ip)); 2ip exact
      unsigned long long cand =
          (((unsigned long long)__float_as_uint(dd)) << 32) | code0;
      if (cand < best[r]) best[r] = cand;      // ties -> lower code = first-index
    }
    // enc-zero stream: 1024 floats per nt (block covers its 256KB region)
    float2* ez = (float2*)(encbase + nt * 1024) + t;
    ez[0] = z2; ez[256] = z2;
    if (nt < 63) {
      bput[(nxt * 6 + w) * 64 + lane] = pv0;
      if (w < 2) bput[(nxt * 6 + w + 4) * 64 + lane] = pv1;
    }
    __syncthreads();
  }

  // ---- per-quad cross-lane u64 argmin (rows w*16 + qd*4 + r) ----
  #pragma unroll
  for (int r = 0; r < 4; ++r) {
    unsigned long long bu = best[r];
    #pragma unroll
    for (int m = 1; m <= 8; m <<= 1) {
      unsigned long long o = __shfl_xor(bu, m, 64);
      if (o < bu) bu = o;
    }
    best[r] = bu;
  }
  if ((lane & 15) == 0) {
    #pragma unroll
    for (int r = 0; r < 4; ++r)
      ((int*)encbase)[w * 16 + qd * 4 + r] = (int)(best[r] & 0xFFFFFFFFu);
  }
}

__global__ __launch_bounds__(256) void vq_out(const float* __restrict__ ze,
                                              const float* __restrict__ emb,
                                              float* __restrict__ ws,
                                              float* __restrict__ out) {
  __shared__ float red[4];
  int g = blockIdx.x, t = threadIdx.x;
  int b = g >> 6, h = g & 63, n0 = g << 6;
  float* enc = out + 8388610;
  int* wp = (int*)(enc + (size_t)n0 * 1024);
  int row = t & 63;
  int gi = wp[row];
  __syncthreads();
  if (t < 64) ((float*)wp)[t] = 0.0f;       // clear winner-stash slots
  __syncthreads();
  if (t < 64) enc[(size_t)(n0 + t) * 1024 + gi] = 1.0f;

  const float* er = emb + gi * 64;
  const float* zr = ze + ((size_t)b << 18) + (h << 6) + row;
  float* qr = out + 1 + ((size_t)b << 18) + (h << 6) + row;
  float ls = 0.0f;
  #pragma unroll
  for (int i = 0; i < 16; ++i) {
    int d = (t >> 6) * 16 + i;
    float v = er[d];
    float df = v - zr[(size_t)d * 4096];
    ls = fmaf(df, df, ls);
    qr[(size_t)d * 4096] = v;
  }
  #pragma unroll
  for (int off = 32; off > 0; off >>= 1) ls += __shfl_down(ls, off, 64);
  if ((t & 63) == 0) red[t >> 6] = ls;
  __syncthreads();
  if (t == 0) atomicAdd(ws, (red[0] + red[1]) + (red[2] + red[3]));
  if (t < 64) atomicAdd((int*)ws + 1 + gi, 1);
}

__global__ __launch_bounds__(1024) void vq_fin(const float* __restrict__ ws,
                                               float* __restrict__ out) {
  __shared__ float sm[16];
  int t = threadIdx.x;  // 0..1023 = k
  const int* counts = (const int*)ws + 1;
  float c = (float)counts[t];
  float p = c * (1.0f / 131072.0f);
  float s = p * logf(p + 1e-10f);
  #pragma unroll
  for (int off = 32; off > 0; off >>= 1) s += __shfl_down(s, off, 64);
  if ((t & 63) == 0) sm[t >> 6] = s;
  __syncthreads();
  if (t == 0) {
    float v = 0.0f;
    #pragma unroll
    for (int i = 0; i < 16; ++i) v += sm[i];
    out[8388609] = expf(-v);               // perplexity
    float m = ws[0] / 8388608.0f;          // mean (z_q - z)^2
    out[0] = 0.25f * m + m;                // commitment + e2z
  }
}

extern "C" void kernel_launch(void* const* d_in, const int* in_sizes, int n_in,
                              void* d_out, int out_size, void* d_ws, size_t ws_size,
                              hipStream_t stream) {
  const float* ze  = (const float*)d_in[0];
  const float* emb = (const float*)d_in[1];
  float* out = (float*)d_out;
  float* ws  = (float*)d_ws;   // 2049 * 4B used
  vq_prep<<<4, 256, 0, stream>>>(emb, ws);
  vq_prep_frags<<<96, 256, 0, stream>>>(emb, out);
  vq_main<<<2048, 256, 0, stream>>>(ze, ws, out);
  vq_out<<<2048, 256, 0, stream>>>(ze, emb, ws, out);
  vq_fin<<<1, 1024, 0, stream>>>(ws, out);
}